// Round 7
// baseline (616.470 us; speedup 1.0000x reference)
//
#include <hip/hip_runtime.h>
#include <stdint.h>

// Persistent-kernel LSTM NAS controller rollout — counter-signaled bulk
// exchange, fence-free.
// r5/r6 lesson: tagged per-cell polling re-sweeps 512 cells x 64 WGs every
// ~0.4us until ready -> 32K sc1 loads/iter contending at MALL with the very
// stores being awaited (~4.5us/hop). This version: producers store f32 cells
// (relaxed agent atomics), s_waitcnt(0)+barrier drain, ONE atomicAdd per WG
// on a per-hop monotone epoch counter; consumers poll ONLY the counter
// (1 lane/WG) then read the data exactly once. No release/acquire fences
// (data-at-MALL before counter-add before counter-observed before sc1 reads).
// Anchors rows are counter-covered by prior ctrC observation -> plain stale
// read, no polling. aw1 rows: own counter ctrW, polled by owner wave only.
// 64 wgs x 512 thr; one hidden unit per wave; weights register-stationary
// (launch_bounds(512,2) -> 256 VGPR cap, no spill).
// RNG: JAX threefry2x32 partitionable (bit-exact, rounds 2-6).

#define KWG    64
#define NTH    512
#define LSTEPS 32
#define DDIM   512
#define NOPS   16
#define NEGC   (-1.0e9f)
#define MAGICV 0x13579BDFu

// ---------------- threefry2x32 core ----------------
static __device__ __forceinline__ void tf2x32(uint32_t k0, uint32_t k1,
                                              uint32_t c0, uint32_t c1,
                                              uint32_t& o0, uint32_t& o1){
  uint32_t ks2 = k0 ^ k1 ^ 0x1BD11BDAu;
  uint32_t x0 = c0 + k0;
  uint32_t x1 = c1 + k1;
#define TFR(r) { x0 += x1; x1 = (x1 << (r)) | (x1 >> (32 - (r))); x1 ^= x0; }
  TFR(13) TFR(15) TFR(26) TFR(6)
  x0 += k1;  x1 += ks2 + 1u;
  TFR(17) TFR(29) TFR(16) TFR(24)
  x0 += ks2; x1 += k0 + 2u;
  TFR(13) TFR(15) TFR(26) TFR(6)
  x0 += k0;  x1 += k1 + 3u;
  TFR(17) TFR(29) TFR(16) TFR(24)
  x0 += k1;  x1 += ks2 + 4u;
  TFR(13) TFR(15) TFR(26) TFR(6)
  x0 += ks2; x1 += k0 + 5u;
#undef TFR
  o0 = x0; o1 = x1;
}

static __device__ __forceinline__ float gumbel_bits(uint32_t bits){
  float f = __uint_as_float((bits >> 9) | 0x3f800000u) - 1.0f;
  float u = (f == 0.0f) ? 1.1754943508222875e-38f : f;
  return -logf(-logf(u));
}

static __device__ __forceinline__ float sigm(float x){
  return 1.0f / (1.0f + expf(-x));
}

static __device__ __forceinline__ float wredsum(float v){
  #pragma unroll
  for (int m = 32; m; m >>= 1) v += __shfl_xor(v, m, 64);
  return v;
}

// gather 8 elems at stride 64: d = 64k + lane  (global or LDS)
static __device__ __forceinline__ void gl8(const float* __restrict__ p, int lane, float* r){
  #pragma unroll
  for (int k = 0; k < 8; ++k) r[k] = p[(k << 6) + lane];
}

static __device__ __forceinline__ float dot8(const float* w, const float* x){
  float s = 0.f;
  #pragma unroll
  for (int k = 0; k < 8; ++k) s += w[k]*x[k];
  return s;
}

// ---------------- relaxed agent-scope atomic helpers (all at MALL) --------
static __device__ __forceinline__ uint32_t aldu(const uint32_t* p){
  return __hip_atomic_load(p, __ATOMIC_RELAXED, __HIP_MEMORY_SCOPE_AGENT);
}
static __device__ __forceinline__ void astu(uint32_t* p, uint32_t v){
  __hip_atomic_store(p, v, __ATOMIC_RELAXED, __HIP_MEMORY_SCOPE_AGENT);
}
static __device__ __forceinline__ float aldf(const float* p){
  return __hip_atomic_load(p, __ATOMIC_RELAXED, __HIP_MEMORY_SCOPE_AGENT);
}
static __device__ __forceinline__ void astf(float* p, float v){
  __hip_atomic_store(p, v, __ATOMIC_RELAXED, __HIP_MEMORY_SCOPE_AGENT);
}
static __device__ __forceinline__ void ctr_add(uint32_t* c){
  __hip_atomic_fetch_add(c, 1u, __ATOMIC_RELAXED, __HIP_MEMORY_SCOPE_AGENT);
}

// producer arrive: drain this WG's data stores to MALL, then one counter add
static __device__ __forceinline__ void hop_arrive(uint32_t* ctr){
  __builtin_amdgcn_s_waitcnt(0);     // vmcnt(0): stores at coherence point
  __syncthreads();                   // all waves drained
  if (threadIdx.x == 0) ctr_add(ctr);
}

// consumer wait: ONE lane polls the epoch counter; then the WG reads data once
static __device__ __forceinline__ void hop_wait(const uint32_t* ctr, uint32_t tgt){
  if (threadIdx.x == 0){
    while (aldu(ctr) < tgt) __builtin_amdgcn_s_sleep(1);
  }
  __syncthreads();
}

__global__ void __launch_bounds__(NTH, 2)
Controller_60601988547087_kernel(const float* __restrict__ emb,
                                 const float* __restrict__ wih,
                                 const float* __restrict__ whh,
                                 const float* __restrict__ bih,
                                 const float* __restrict__ bhh,
                                 const float* __restrict__ wa1,
                                 const float* __restrict__ wa2,
                                 const float* __restrict__ idxfc,
                                 const float* __restrict__ opfc,
                                 float* __restrict__ out,
                                 uint32_t* __restrict__ wsu)
{
  const int tid  = threadIdx.x;
  const int wg   = blockIdx.x;
  const int wave = tid >> 6;              // 0..7
  const int lane = tid & 63;
  const int unit = (wg << 3) | wave;      // one hidden unit per wave, 512 total

  // workspace: counters on separate 64B lines, then magic flags, then f32 data
  uint32_t* ctrA   = wsu;                 // h1 epochs      (target 64*(t+1))
  uint32_t* ctrB   = wsu + 16;            // hw2 epochs     (target 64*(t+1))
  uint32_t* ctrC   = wsu + 32;            // h2/anch epochs (init 64; step t -> 64*(t+2))
  uint32_t* ctrW   = wsu + 48;            // aw1 row epochs (row r ready at 64*(r+1))
  uint32_t* magicf = wsu + 64;            // [64] stride 16
  float*    wsf    = (float*)(wsu + 2048);
  float*    bufA   = wsf;                 // h1      [512]
  float*    bufB   = wsf + 512;           // h2      [512]
  float*    hw2g   = wsf + 1024;          // W2.h1   [512]
  float*    aw1g   = wsf + 1536;          // aw1 rows[32][512]
  float*    anch   = wsf + 1536 + 32*512; // anchors [32][512] (row0 unused)

  __shared__ float s_hc[DDIM];            // carry h / h2 staging
  __shared__ float s_h1[DDIM];            // h after cell1
  __shared__ float s_hw2[DDIM];           // h1 @ w_attn_2^T
  __shared__ float s_arow[DDIM];          // anchors[ni]
  __shared__ float s_xproj[17 * 32];      // [op][wave][gate] static W_ih·emb[op]
  __shared__ float s_opfc[NOPS * DDIM];   // 32 KB op_fc
  __shared__ float s_logits[33];
  __shared__ float s_oplog[16];
  __shared__ int   s_ibc[2];

  // ---- weights register-stationary, gathered at d = 64k+lane ----
  float wihr[4][8], whhr[4][8], a1r[8], a2r[8], fcr[8], bsum[4];
  #pragma unroll
  for (int g = 0; g < 4; ++g){
    gl8(wih + (size_t)((g << 9) + unit) * DDIM, lane, wihr[g]);
    gl8(whh + (size_t)((g << 9) + unit) * DDIM, lane, whhr[g]);
    bsum[g] = bih[(g << 9) + unit] + bhh[(g << 9) + unit];
  }
  gl8(wa1 + (size_t)unit * DDIM, lane, a1r);
  gl8(wa2 + (size_t)unit * DDIM, lane, a2r);
  gl8(idxfc, lane, fcr);

  for (int i = tid; i < NOPS * DDIM; i += NTH) s_opfc[i] = opfc[i];

  // ---- static x-projections: s_xproj[op][wave][g] = (W_ih · emb[op])[unit] ----
  for (int op = 0; op <= NOPS; ++op){
    float xc[8];
    gl8(emb + (size_t)op * DDIM, lane, xc);
    #pragma unroll
    for (int g = 0; g < 4; ++g){
      float xp = wredsum(dot8(wihr[g], xc));
      if (lane == 0) s_xproj[op * 32 + (wave << 2) + g] = xp;
    }
  }
  __syncthreads();

  // per-wave register cache of aw1 rows (row r owned by wave r&7, slot r>>3)
  float row0[8], row1[8], row2[8], row3[8];

  // ---- init: zero counters (0xAA poison!), magic barrier ----
  if (wg == 0 && tid == 0){
    astu(ctrA, 0u); astu(ctrB, 0u); astu(ctrC, 0u); astu(ctrW, 0u);
  }
  __builtin_amdgcn_s_waitcnt(0);
  __syncthreads();
  if (tid == 0) astu(magicf + (wg << 4), MAGICV);
  if (tid < KWG){
    while (aldu(magicf + (tid << 4)) != MAGICV) __builtin_amdgcn_s_sleep(1);
  }
  __syncthreads();

  // ---- h0 = cell(emb[16],0,0) via xproj; publish bufB, ctrC -> 64 ----
  float cst;
  {
    const float* xp = s_xproj + 16 * 32 + (wave << 2);
    float gi = sigm(xp[0] + bsum[0]);
    float go = sigm(xp[3] + bsum[3]);
    cst = gi * tanhf(xp[2] + bsum[2]);   // c=0: forget term vanishes exactly
    float h0 = go * tanhf(cst);
    if (lane == 0) astf(bufB + unit, h0);
  }
  hop_arrive(ctrC);
  hop_wait(ctrC, 64u);
  s_hc[tid] = aldf(bufB + tid);
  __syncthreads();

  // aw1 row 0 = W1 · h0; publish, ctrW -> 64; owner (wave0) caches slot0
  {
    float hcv[8];
    gl8(s_hc, lane, hcv);
    float pa = wredsum(dot8(a1r, hcv));
    if (lane == 0) astf(aw1g + unit, pa);
  }
  hop_arrive(ctrW);
  hop_wait(ctrW, 64u);
  if (wave == 0) gl8_atomic: {
    #pragma unroll
    for (int k = 0; k < 8; ++k) row0[k] = aldf(aw1g + (k << 6) + lane);
  }

  uint32_t key0 = 0u, key1v = 42u;       // jax.random.key(42) -> (0, 42)
  float ent_sum = 0.f, lp_sum = 0.f;
  int prev_op = NOPS;                    // inp0 = embedding[16]

  for (int t = 0; t < LSTEPS; ++t){
    const uint32_t tgtAB = 64u * (uint32_t)(t + 1);
    const uint32_t tgtC  = 64u * (uint32_t)(t + 2);

    // ========== Stage A: cell1 = xproj[prev_op] + W_hh·h_carry ==========
    {
      float hcv[8];
      gl8(s_hc, lane, hcv);
      const float* xp = s_xproj + prev_op * 32 + (wave << 2);
      float p0 = wredsum(dot8(whhr[0], hcv));
      float p1 = wredsum(dot8(whhr[1], hcv));
      float p2 = wredsum(dot8(whhr[2], hcv));
      float p3 = wredsum(dot8(whhr[3], hcv));
      float gi = sigm(xp[0] + p0 + bsum[0]);
      float gf = sigm(xp[1] + p1 + bsum[1]);
      float go = sigm(xp[3] + p3 + bsum[3]);
      cst = gf * cst + gi * tanhf(xp[2] + p2 + bsum[2]);
      float hn = go * tanhf(cst);
      if (lane == 0) astf(bufA + unit, hn);
    }
    hop_arrive(ctrA);
    // shadow of ctrA wait: owner wave fetches aw1 row t (counter-covered)
    if (t > 0 && wave == (t & 7)){
      if (lane == 0){
        while (aldu(ctrW) < tgtAB) __builtin_amdgcn_s_sleep(1);
      }
      const float* rb = aw1g + (size_t)t * DDIM;
      float rr[8];
      #pragma unroll
      for (int k = 0; k < 8; ++k) rr[k] = aldf(rb + (k << 6) + lane);
      int slot = t >> 3;
      #pragma unroll
      for (int k = 0; k < 8; ++k){
        if      (slot == 0) row0[k] = rr[k];
        else if (slot == 1) row1[k] = rr[k];
        else if (slot == 2) row2[k] = rr[k];
        else                row3[k] = rr[k];
      }
    }
    hop_wait(ctrA, tgtAB);               // hop A
    s_h1[tid] = aldf(bufA + tid);
    __syncthreads();

    // ========== Stage B: publish hw2 slice; ghh before the wait ==========
    float ghh0, ghh1, ghh2, ghh3;
    float h1c[8];
    gl8(s_h1, lane, h1c);
    {
      float q = wredsum(dot8(a2r, h1c));
      if (lane == 0) astf(hw2g + unit, q);
    }
    hop_arrive(ctrB);
    ghh0 = wredsum(dot8(whhr[0], h1c));  // overlaps other WGs' publishes
    ghh1 = wredsum(dot8(whhr[1], h1c));
    ghh2 = wredsum(dot8(whhr[2], h1c));
    ghh3 = wredsum(dot8(whhr[3], h1c));
    hop_wait(ctrB, tgtAB);               // hop B
    s_hw2[tid] = aldf(hw2g + tid);
    __syncthreads();

    // ======== Node logits + sampling — EVERY WG, bit-identical ========
    int ni;
    float nlp_s = 0.f, nent_s = 0.f;
    uint32_t k2a_s = 0u, k2b_s = 0u;
    {
      float h2c[8];
      gl8(s_hw2, lane, h2c);
#define ROWDOT(RR, I)                                                          \
      { int i_ = (I);                                                          \
        if (i_ <= t){                                                          \
          float acc = 0.f;                                                     \
          _Pragma("unroll")                                                    \
          for (int k = 0; k < 8; ++k) acc += tanhf(RR[k] + h2c[k]) * fcr[k];   \
          acc = wredsum(acc);                                                  \
          if (lane == 0) s_logits[i_] = 2.5f * tanhf(acc / 5.0f);              \
        } }
      ROWDOT(row0, wave)
      ROWDOT(row1, wave + 8)
      ROWDOT(row2, wave + 16)
      ROWDOT(row3, wave + 24)
#undef ROWDOT
      __syncthreads();
      if (wave == 0){
        // split(key,3), partitionable/foldlike: row i = tf(key, (0, i))
        uint32_t s0 = 0, s1 = 0;
        if (lane < 3) tf2x32(key0, key1v, 0u, (uint32_t)lane, s0, s1);
        uint32_t k1a = __shfl(s0, 0, 64), k1b = __shfl(s1, 0, 64);
        k2a_s = __shfl(s0, 1, 64); k2b_s = __shfl(s1, 1, 64);
        uint32_t nk0 = __shfl(s0, 2, 64), nk1 = __shfl(s1, 2, 64);
        key0 = nk0; key1v = nk1;
        // 33 random bits: bits[i] = x0 ^ x1 of tf(k1, (0, i))
        uint32_t y0 = 0, y1 = 0;
        if (lane < 33) tf2x32(k1a, k1b, 0u, (uint32_t)lane, y0, y1);
        uint32_t bits = y0 ^ y1;
        float gmb   = gumbel_bits(bits);
        float logit = (lane < 33) ? ((lane <= t) ? s_logits[lane] : NEGC) : -3.0e38f;
        float cand  = (lane < 33) ? (logit + gmb) : -3.0e38f;
        float v = cand; int bi = lane;
        #pragma unroll
        for (int m = 32; m; m >>= 1){
          float ov = __shfl_xor(v, m, 64); int ob = __shfl_xor(bi, m, 64);
          if (ov > v || (ov == v && ob < bi)){ v = ov; bi = ob; }
        }
        int ni_ = bi;
        float lm = (lane < 33) ? logit : -3.0e38f;
        #pragma unroll
        for (int m = 32; m; m >>= 1) lm = fmaxf(lm, __shfl_xor(lm, m, 64));
        float ex   = (lane < 33) ? expf(logit - lm) : 0.f;
        float ssum = wredsum(ex);
        float lsm  = logit - lm - logf(ssum);
        nlp_s  = -__shfl(lsm, ni_, 64);
        float entc = (lane <= t) ? (-lsm * expf(lsm)) : 0.f;
        nent_s = wredsum(entc);
        if (lane == 0) s_ibc[0] = ni_;
      }
      __syncthreads();
      ni = s_ibc[0];
    }

    // ========== Stage C: cell2 (op_in = anchors[ni]) ==========
    // anch row r>=1 was published at step r-1 under ctrC>=64*(r+1); we have
    // already observed ctrC >= 64*(t+1) and r<=t -> plain stale read, no poll.
    s_arow[tid] = (ni > 0) ? aldf(anch + (size_t)ni * DDIM + tid) : 0.f;
    __syncthreads();
    {
      float oc8[8];
      gl8(s_arow, lane, oc8);
      float q0 = wredsum(dot8(wihr[0], oc8));
      float q1 = wredsum(dot8(wihr[1], oc8));
      float q2 = wredsum(dot8(wihr[2], oc8));
      float q3 = wredsum(dot8(wihr[3], oc8));
      float gi = sigm(q0 + ghh0 + bsum[0]);
      float gf = sigm(q1 + ghh1 + bsum[1]);
      float go = sigm(q3 + ghh3 + bsum[3]);
      cst = gf * cst + gi * tanhf(q2 + ghh2 + bsum[2]);
      float hn = go * tanhf(cst);
      if (lane == 0){
        astf(bufB + unit, hn);
        if (t < LSTEPS - 1) astf(anch + (size_t)(t + 1) * DDIM + unit, hn);
      }
    }
    hop_arrive(ctrC);
    hop_wait(ctrC, tgtC);                // hop C
    s_hc[tid] = aldf(bufB + tid);
    __syncthreads();

    // ========== Tail: aw1 row t+1 publish (ctrW), op logits + sample ======
    {
      float hc2[8];
      gl8(s_hc, lane, hc2);
      if (t < LSTEPS - 1){
        float pa = wredsum(dot8(a1r, hc2));               // W1·h2 = aw1[t+1]
        if (lane == 0) astf(aw1g + (size_t)(t + 1) * DDIM + unit, pa);
        hop_arrive(ctrW);                // bump early: unblocks next step's owner
      }
      #pragma unroll
      for (int jj = 0; jj < 2; ++jj){
        int i = wave + (jj << 3);
        float acc = 0.f;
        #pragma unroll
        for (int k = 0; k < 8; ++k) acc += s_opfc[i * DDIM + (k << 6) + lane] * hc2[k];
        acc = wredsum(acc);
        if (lane == 0) s_oplog[i] = tanhf(acc / 5.0f);    // (2.5/2.5)=1 scale
      }
      __syncthreads();
    }
    int oi;
    {
      if (wave == 0){
        // 16 random bits: bits[i] = x0 ^ x1 of tf(k2, (0, i))
        uint32_t z0 = 0, z1 = 0;
        if (lane < 16) tf2x32(k2a_s, k2b_s, 0u, (uint32_t)lane, z0, z1);
        uint32_t bits = z0 ^ z1;
        float gmb   = gumbel_bits(bits);
        float logit = (lane < 16) ? s_oplog[lane] : -3.0e38f;
        float cand  = (lane < 16) ? (logit + gmb) : -3.0e38f;
        float v = cand; int bi = lane;
        #pragma unroll
        for (int m = 32; m; m >>= 1){
          float ov = __shfl_xor(v, m, 64); int ob = __shfl_xor(bi, m, 64);
          if (ov > v || (ov == v && ob < bi)){ v = ov; bi = ob; }
        }
        int oi_ = bi;
        float lm = (lane < 16) ? logit : -3.0e38f;
        #pragma unroll
        for (int m = 32; m; m >>= 1) lm = fmaxf(lm, __shfl_xor(lm, m, 64));
        float ex   = (lane < 16) ? expf(logit - lm) : 0.f;
        float ssum = wredsum(ex);
        float olsm = logit - lm - logf(ssum);
        float olp  = -__shfl(olsm, oi_, 64);
        float oent = wredsum((lane < 16) ? (-olsm * expf(olsm)) : 0.f);
        lp_sum  += nlp_s + olp;
        ent_sum += nent_s + oent;
        if (lane == 0){
          s_ibc[1] = oi_;
          if (wg == 0){
            out[2 * t]     = (float)ni;
            out[2 * t + 1] = (float)oi_;
          }
        }
      }
      __syncthreads();
      oi = s_ibc[1];
    }
    prev_op = oi;
  }

  if (wg == 0 && wave == 0 && lane == 0){
    out[64] = ent_sum;
    out[65] = lp_sum;
  }
}

extern "C" void kernel_launch(void* const* d_in, const int* in_sizes, int n_in,
                              void* d_out, int out_size, void* d_ws, size_t ws_size,
                              hipStream_t stream) {
  (void)in_sizes; (void)n_in; (void)out_size; (void)ws_size;
  const float* emb  = (const float*)d_in[0];
  const float* wih  = (const float*)d_in[1];
  const float* whh  = (const float*)d_in[2];
  const float* bih  = (const float*)d_in[3];
  const float* bhh  = (const float*)d_in[4];
  const float* wa1  = (const float*)d_in[5];
  const float* wa2  = (const float*)d_in[6];
  const float* ifc  = (const float*)d_in[7];
  const float* ofc  = (const float*)d_in[8];
  float* out = (float*)d_out;
  uint32_t* ws = (uint32_t*)d_ws;
  hipLaunchKernelGGL(Controller_60601988547087_kernel,
                     dim3(KWG), dim3(NTH), 0, stream,
                     emb, wih, whh, bih, bhh, wa1, wa2, ifc, ofc, out, ws);
}

// Round 8
// 537.029 us; speedup vs baseline: 1.1479x; 1.1479x over previous
//
#include <hip/hip_runtime.h>
#include <stdint.h>

// Persistent-kernel LSTM NAS controller rollout — tagged-cell dataflow (r5
// mechanism, measured best) + critical-path surgery.
// r5/r6/r7 triangulation: per-hop ~4.4us is mechanism-invariant (sc1 store ->
// MALL visible -> remote observe -> read, plus 64-WG skew). 3 hops/step are
// structurally forced (full h1, full hw2, full h2). This round removes all
// remaining off-hop critical-path work:
//  - aproj cache: (W_ih . anchors[r])[unit] computed once in hop-A shadow when
//    h2^(r-1) arrives -> stage C = ~20 ALU ops, no anchors read, no wredsums.
//  - aw1 row t publish + aproj row t moved to hop-A shadow (s_hc available).
//  - tail = op logits + sample only.
// 64 wgs x 512 thr; one hidden unit per wave; weights register-stationary
// (launch_bounds(512,2) -> 256 VGPR cap). Tags: A=3t+2, B=3t+3, C=3t+4,
// init h0 tag=1; poison 0xAAAAAAAA never matches; monotone-overwrite safe
// (producers cannot advance a cell's tag past an unconsumed epoch because
// every step requires all 512 waves' participation).
// RNG: JAX threefry2x32 partitionable (bit-exact, rounds 2-7).

#define KWG    64
#define NTH    512
#define LSTEPS 32
#define DDIM   512
#define NOPS   16
#define NEGC   (-1.0e9f)

// ---------------- threefry2x32 core ----------------
static __device__ __forceinline__ void tf2x32(uint32_t k0, uint32_t k1,
                                              uint32_t c0, uint32_t c1,
                                              uint32_t& o0, uint32_t& o1){
  uint32_t ks2 = k0 ^ k1 ^ 0x1BD11BDAu;
  uint32_t x0 = c0 + k0;
  uint32_t x1 = c1 + k1;
#define TFR(r) { x0 += x1; x1 = (x1 << (r)) | (x1 >> (32 - (r))); x1 ^= x0; }
  TFR(13) TFR(15) TFR(26) TFR(6)
  x0 += k1;  x1 += ks2 + 1u;
  TFR(17) TFR(29) TFR(16) TFR(24)
  x0 += ks2; x1 += k0 + 2u;
  TFR(13) TFR(15) TFR(26) TFR(6)
  x0 += k0;  x1 += k1 + 3u;
  TFR(17) TFR(29) TFR(16) TFR(24)
  x0 += k1;  x1 += ks2 + 4u;
  TFR(13) TFR(15) TFR(26) TFR(6)
  x0 += ks2; x1 += k0 + 5u;
#undef TFR
  o0 = x0; o1 = x1;
}

static __device__ __forceinline__ float gumbel_bits(uint32_t bits){
  float f = __uint_as_float((bits >> 9) | 0x3f800000u) - 1.0f;
  float u = (f == 0.0f) ? 1.1754943508222875e-38f : f;
  return -logf(-logf(u));
}

static __device__ __forceinline__ float sigm(float x){
  return 1.0f / (1.0f + expf(-x));
}

static __device__ __forceinline__ float wredsum(float v){
  #pragma unroll
  for (int m = 32; m; m >>= 1) v += __shfl_xor(v, m, 64);
  return v;
}

// gather 8 elems at stride 64: d = 64k + lane  (global or LDS)
static __device__ __forceinline__ void gl8(const float* __restrict__ p, int lane, float* r){
  #pragma unroll
  for (int k = 0; k < 8; ++k) r[k] = p[(k << 6) + lane];
}

static __device__ __forceinline__ float dot8(const float* w, const float* x){
  float s = 0.f;
  #pragma unroll
  for (int k = 0; k < 8; ++k) s += w[k]*x[k];
  return s;
}

// ---------------- tagged-atomic helpers (relaxed agent, at MALL) ----------
static __device__ __forceinline__ uint64_t tpack(uint32_t tag, float f){
  return ((uint64_t)tag << 32) | (uint64_t)__float_as_uint(f);
}
static __device__ __forceinline__ uint64_t ald64(const uint64_t* p){
  return __hip_atomic_load(p, __ATOMIC_RELAXED, __HIP_MEMORY_SCOPE_AGENT);
}
static __device__ __forceinline__ void ast64(uint64_t* p, uint64_t v){
  __hip_atomic_store(p, v, __ATOMIC_RELAXED, __HIP_MEMORY_SCOPE_AGENT);
}
static __device__ __forceinline__ float poll1(const uint64_t* p, uint32_t tag){
  uint64_t v = ald64(p);
  while ((uint32_t)(v >> 32) != tag){
    __builtin_amdgcn_s_sleep(1);
    v = ald64(p);
  }
  return __uint_as_float((uint32_t)v);
}
// poll 8 cells (d=64k+lane) into registers (aw1 register rows)
static __device__ __forceinline__ void poll8s(const uint64_t* base, int lane,
                                              uint32_t tag, float* r){
  uint64_t v[8];
  for (;;){
    #pragma unroll
    for (int k = 0; k < 8; ++k) v[k] = ald64(base + (k << 6) + lane);
    bool ok = true;
    #pragma unroll
    for (int k = 0; k < 8; ++k) ok &= ((uint32_t)(v[k] >> 32) == tag);
    if (ok) break;
    __builtin_amdgcn_s_sleep(1);
  }
  #pragma unroll
  for (int k = 0; k < 8; ++k) r[k] = __uint_as_float((uint32_t)v[k]);
}

__global__ void __launch_bounds__(NTH, 2)
Controller_60601988547087_kernel(const float* __restrict__ emb,
                                 const float* __restrict__ wih,
                                 const float* __restrict__ whh,
                                 const float* __restrict__ bih,
                                 const float* __restrict__ bhh,
                                 const float* __restrict__ wa1,
                                 const float* __restrict__ wa2,
                                 const float* __restrict__ idxfc,
                                 const float* __restrict__ opfc,
                                 float* __restrict__ out,
                                 uint64_t* __restrict__ ws64)
{
  const int tid  = threadIdx.x;
  const int wg   = blockIdx.x;
  const int wave = tid >> 6;              // 0..7
  const int lane = tid & 63;
  const int unit = (wg << 3) | wave;      // one hidden unit per wave, 512 total

  // workspace (u64 tagged cells)
  uint64_t* bufA64 = ws64;                // h1      [512]  tags 3t+2
  uint64_t* bufB64 = ws64 + 512;          // h2      [512]  tags 1, 3t+4
  uint64_t* hw2g64 = ws64 + 1024;         // W2.h1   [512]  tags 3t+3
  uint64_t* aw1g64 = ws64 + 1536;         // aw1 rows[32][512], row t tag 3t+2

  __shared__ float s_hc[DDIM];            // carry h (h2) staging
  __shared__ float s_h1[DDIM];            // h after cell1
  __shared__ float s_hw2[DDIM];           // h1 @ w_attn_2^T
  __shared__ float s_xproj[17 * 32];      // [op][wave][gate] static W_ih·emb[op]
  __shared__ float s_aproj[33 * 32];      // [row][wave][gate] W_ih·anchors[row]
  __shared__ float s_opfc[NOPS * DDIM];   // 32 KB op_fc
  __shared__ float s_logits[33];
  __shared__ float s_oplog[16];
  __shared__ int   s_ibc[2];

  // ---- weights register-stationary, gathered at d = 64k+lane ----
  float wihr[4][8], whhr[4][8], a1r[8], a2r[8], fcr[8], bsum[4];
  #pragma unroll
  for (int g = 0; g < 4; ++g){
    gl8(wih + (size_t)((g << 9) + unit) * DDIM, lane, wihr[g]);
    gl8(whh + (size_t)((g << 9) + unit) * DDIM, lane, whhr[g]);
    bsum[g] = bih[(g << 9) + unit] + bhh[(g << 9) + unit];
  }
  gl8(wa1 + (size_t)unit * DDIM, lane, a1r);
  gl8(wa2 + (size_t)unit * DDIM, lane, a2r);
  gl8(idxfc, lane, fcr);

  for (int i = tid; i < NOPS * DDIM; i += NTH) s_opfc[i] = opfc[i];
  if (tid < 32) s_aproj[tid] = 0.0f;      // aproj row 0: anchors[0] = zeros

  // ---- static x-projections: s_xproj[op][wave][g] = (W_ih · emb[op])[unit] ----
  for (int op = 0; op <= NOPS; ++op){
    float xc[8];
    gl8(emb + (size_t)op * DDIM, lane, xc);
    #pragma unroll
    for (int g = 0; g < 4; ++g){
      float xp = wredsum(dot8(wihr[g], xc));
      if (lane == 0) s_xproj[op * 32 + (wave << 2) + g] = xp;
    }
  }
  __syncthreads();

  // per-wave register cache of aw1 rows (row r owned by wave r&7, slot r>>3)
  float row0[8], row1[8], row2[8], row3[8];

  // ---- init: h0 = cell(emb[16],0,0) via xproj; publish bufB tag 1 ----
  float cst;
  {
    const float* xp = s_xproj + 16 * 32 + (wave << 2);
    float gi = sigm(xp[0] + bsum[0]);
    float go = sigm(xp[3] + bsum[3]);
    cst = gi * tanhf(xp[2] + bsum[2]);   // c=0: forget term vanishes exactly
    float h0 = go * tanhf(cst);
    if (lane == 0) ast64(bufB64 + unit, tpack(1u, h0));
  }
  s_hc[tid] = poll1(bufB64 + tid, 1u);   // stage carry h (= h0)
  __syncthreads();

  uint32_t key0 = 0u, key1v = 42u;       // jax.random.key(42) -> (0, 42)
  float ent_sum = 0.f, lp_sum = 0.f;
  int prev_op = NOPS;                    // inp0 = embedding[16]

  for (int t = 0; t < LSTEPS; ++t){
    const uint32_t tagA = 3u*(uint32_t)t + 2u;
    const uint32_t tagB = 3u*(uint32_t)t + 3u;
    const uint32_t tagC = 3u*(uint32_t)t + 4u;

    float hc8[8];
    gl8(s_hc, lane, hc8);                // h2^(t-1) (= anchors[t] for t>=1; h0 at t=0)

    // ========== Stage A (critical): cell1 = xproj[prev_op] + W_hh·h ==========
    {
      const float* xp = s_xproj + prev_op * 32 + (wave << 2);
      float p0 = wredsum(dot8(whhr[0], hc8));
      float p1 = wredsum(dot8(whhr[1], hc8));
      float p2 = wredsum(dot8(whhr[2], hc8));
      float p3 = wredsum(dot8(whhr[3], hc8));
      float gi = sigm(xp[0] + p0 + bsum[0]);
      float gf = sigm(xp[1] + p1 + bsum[1]);
      float go = sigm(xp[3] + p3 + bsum[3]);
      cst = gf * cst + gi * tanhf(xp[2] + p2 + bsum[2]);
      float hn = go * tanhf(cst);
      if (lane == 0) ast64(bufA64 + unit, tpack(tagA, hn));
    }
    // ---- hop-A shadow: aw1 row t publish, aproj row t, owner row fetch ----
    {
      float pa = wredsum(dot8(a1r, hc8));              // row t = W1·h2^(t-1)
      if (lane == 0) ast64(aw1g64 + (size_t)t * DDIM + unit, tpack(tagA, pa));
      if (t > 0){                                      // aproj[t] = W_ih·anchors[t]
        #pragma unroll
        for (int g = 0; g < 4; ++g){
          float ap = wredsum(dot8(wihr[g], hc8));
          if (lane == 0) s_aproj[t * 32 + (wave << 2) + g] = ap;
        }
      }
    }
    if (wave == (t & 7)){                              // owner caches row t
      const uint64_t* rb = aw1g64 + (size_t)t * DDIM;
      int slot = t >> 3;
      if      (slot == 0) poll8s(rb, lane, tagA, row0);
      else if (slot == 1) poll8s(rb, lane, tagA, row1);
      else if (slot == 2) poll8s(rb, lane, tagA, row2);
      else                poll8s(rb, lane, tagA, row3);
    }
    s_h1[tid] = poll1(bufA64 + tid, tagA);             // hop A
    __syncthreads();

    // ========== Stage B: publish hw2 slice; ghh in hop-B shadow ==========
    float ghh0, ghh1, ghh2, ghh3;
    float h18[8];
    gl8(s_h1, lane, h18);
    {
      float q = wredsum(dot8(a2r, h18));
      if (lane == 0) ast64(hw2g64 + unit, tpack(tagB, q));
    }
    ghh0 = wredsum(dot8(whhr[0], h18));                // shadow of hop B
    ghh1 = wredsum(dot8(whhr[1], h18));
    ghh2 = wredsum(dot8(whhr[2], h18));
    ghh3 = wredsum(dot8(whhr[3], h18));
    s_hw2[tid] = poll1(hw2g64 + tid, tagB);            // hop B
    __syncthreads();

    // ======== Node logits + sampling — EVERY WG, bit-identical ========
    int ni;
    float nlp_s = 0.f, nent_s = 0.f;
    uint32_t k2a_s = 0u, k2b_s = 0u;
    {
      float h2c[8];
      gl8(s_hw2, lane, h2c);
#define ROWDOT(RR, I)                                                          \
      { int i_ = (I);                                                          \
        if (i_ <= t){                                                          \
          float acc = 0.f;                                                     \
          _Pragma("unroll")                                                    \
          for (int k = 0; k < 8; ++k) acc += tanhf(RR[k] + h2c[k]) * fcr[k];   \
          acc = wredsum(acc);                                                  \
          if (lane == 0) s_logits[i_] = 2.5f * tanhf(acc / 5.0f);              \
        } }
      ROWDOT(row0, wave)
      ROWDOT(row1, wave + 8)
      ROWDOT(row2, wave + 16)
      ROWDOT(row3, wave + 24)
#undef ROWDOT
      __syncthreads();
      if (wave == 0){
        // split(key,3), partitionable/foldlike: row i = tf(key, (0, i))
        uint32_t s0 = 0, s1 = 0;
        if (lane < 3) tf2x32(key0, key1v, 0u, (uint32_t)lane, s0, s1);
        uint32_t k1a = __shfl(s0, 0, 64), k1b = __shfl(s1, 0, 64);
        k2a_s = __shfl(s0, 1, 64); k2b_s = __shfl(s1, 1, 64);
        uint32_t nk0 = __shfl(s0, 2, 64), nk1 = __shfl(s1, 2, 64);
        key0 = nk0; key1v = nk1;
        // 33 random bits: bits[i] = x0 ^ x1 of tf(k1, (0, i))
        uint32_t y0 = 0, y1 = 0;
        if (lane < 33) tf2x32(k1a, k1b, 0u, (uint32_t)lane, y0, y1);
        uint32_t bits = y0 ^ y1;
        float gmb   = gumbel_bits(bits);
        float logit = (lane < 33) ? ((lane <= t) ? s_logits[lane] : NEGC) : -3.0e38f;
        float cand  = (lane < 33) ? (logit + gmb) : -3.0e38f;
        float v = cand; int bi = lane;
        #pragma unroll
        for (int m = 32; m; m >>= 1){
          float ov = __shfl_xor(v, m, 64); int ob = __shfl_xor(bi, m, 64);
          if (ov > v || (ov == v && ob < bi)){ v = ov; bi = ob; }
        }
        int ni_ = bi;
        float lm = (lane < 33) ? logit : -3.0e38f;
        #pragma unroll
        for (int m = 32; m; m >>= 1) lm = fmaxf(lm, __shfl_xor(lm, m, 64));
        float ex   = (lane < 33) ? expf(logit - lm) : 0.f;
        float ssum = wredsum(ex);
        float lsm  = logit - lm - logf(ssum);
        nlp_s  = -__shfl(lsm, ni_, 64);
        float entc = (lane <= t) ? (-lsm * expf(lsm)) : 0.f;
        nent_s = wredsum(entc);
        if (lane == 0) s_ibc[0] = ni_;
      }
      __syncthreads();
      ni = s_ibc[0];
    }

    // ========== Stage C (critical, tiny): cell2 via aproj cache ==========
    {
      const float* ag = s_aproj + ni * 32 + (wave << 2);
      float gi = sigm(ag[0] + ghh0 + bsum[0]);
      float gf = sigm(ag[1] + ghh1 + bsum[1]);
      float go = sigm(ag[3] + ghh3 + bsum[3]);
      cst = gf * cst + gi * tanhf(ag[2] + ghh2 + bsum[2]);
      float hn = go * tanhf(cst);
      if (lane == 0) ast64(bufB64 + unit, tpack(tagC, hn));
    }
    s_hc[tid] = poll1(bufB64 + tid, tagC);             // hop C
    __syncthreads();

    // ========== Tail (critical): op logits + sample -> prev_op ==========
    {
      float h28[8];
      gl8(s_hc, lane, h28);
      #pragma unroll
      for (int jj = 0; jj < 2; ++jj){
        int i = wave + (jj << 3);
        float acc = 0.f;
        #pragma unroll
        for (int k = 0; k < 8; ++k) acc += s_opfc[i * DDIM + (k << 6) + lane] * h28[k];
        acc = wredsum(acc);
        if (lane == 0) s_oplog[i] = tanhf(acc / 5.0f);  // (2.5/2.5)=1 scale
      }
      __syncthreads();
    }
    int oi;
    {
      if (wave == 0){
        // 16 random bits: bits[i] = x0 ^ x1 of tf(k2, (0, i))
        uint32_t z0 = 0, z1 = 0;
        if (lane < 16) tf2x32(k2a_s, k2b_s, 0u, (uint32_t)lane, z0, z1);
        uint32_t bits = z0 ^ z1;
        float gmb   = gumbel_bits(bits);
        float logit = (lane < 16) ? s_oplog[lane] : -3.0e38f;
        float cand  = (lane < 16) ? (logit + gmb) : -3.0e38f;
        float v = cand; int bi = lane;
        #pragma unroll
        for (int m = 32; m; m >>= 1){
          float ov = __shfl_xor(v, m, 64); int ob = __shfl_xor(bi, m, 64);
          if (ov > v || (ov == v && ob < bi)){ v = ov; bi = ob; }
        }
        int oi_ = bi;
        float lm = (lane < 16) ? logit : -3.0e38f;
        #pragma unroll
        for (int m = 32; m; m >>= 1) lm = fmaxf(lm, __shfl_xor(lm, m, 64));
        float ex   = (lane < 16) ? expf(logit - lm) : 0.f;
        float ssum = wredsum(ex);
        float olsm = logit - lm - logf(ssum);
        float olp  = -__shfl(olsm, oi_, 64);
        float oent = wredsum((lane < 16) ? (-olsm * expf(olsm)) : 0.f);
        lp_sum  += nlp_s + olp;
        ent_sum += nent_s + oent;
        if (lane == 0){
          s_ibc[1] = oi_;
          if (wg == 0){
            out[2 * t]     = (float)ni;
            out[2 * t + 1] = (float)oi_;
          }
        }
      }
      __syncthreads();
      oi = s_ibc[1];
    }
    prev_op = oi;
  }

  if (wg == 0 && wave == 0 && lane == 0){
    out[64] = ent_sum;
    out[65] = lp_sum;
  }
}

extern "C" void kernel_launch(void* const* d_in, const int* in_sizes, int n_in,
                              void* d_out, int out_size, void* d_ws, size_t ws_size,
                              hipStream_t stream) {
  (void)in_sizes; (void)n_in; (void)out_size; (void)ws_size;
  const float* emb  = (const float*)d_in[0];
  const float* wih  = (const float*)d_in[1];
  const float* whh  = (const float*)d_in[2];
  const float* bih  = (const float*)d_in[3];
  const float* bhh  = (const float*)d_in[4];
  const float* wa1  = (const float*)d_in[5];
  const float* wa2  = (const float*)d_in[6];
  const float* ifc  = (const float*)d_in[7];
  const float* ofc  = (const float*)d_in[8];
  float* out = (float*)d_out;
  uint64_t* ws = (uint64_t*)d_ws;
  hipLaunchKernelGGL(Controller_60601988547087_kernel,
                     dim3(KWG), dim3(NTH), 0, stream,
                     emb, wih, whh, bih, bhh, wa1, wa2, ifc, ofc, out, ws);
}

// Round 9
// 533.330 us; speedup vs baseline: 1.1559x; 1.0069x over previous
//
#include <hip/hip_runtime.h>
#include <stdint.h>

// Persistent-kernel LSTM NAS controller rollout — tagged-cell dataflow with
// ATOMIC-SWAP publishes (A/B vs r8's plain sc1 stores).
// r5-r8 triangulation: per-hop ~4.4us is invariant to poll traffic (r6),
// counter signaling (r7, +0.4us = extra serial round trip), and off-path
// compute (r8). Consumer read latency ~0.3us. Remaining suspect: producer
// sc1 relaxed STORES drain lazily to MALL. RMW (atomic swap) must commit at
// the coherence point synchronously -> publishes become promptly visible.
// Everything else identical to r8:
//  - aproj cache (W_ih.anchors in LDS), xproj static table, aw1 rows in
//    per-wave registers, op_fc in LDS, tail = op logits + sample only.
//  - 64 wgs x 512 thr; one unit per wave; weights register-stationary.
//  - Tags: A=3t+2, B=3t+3, C=3t+4; init tag 1; poison never matches.
// RNG: JAX threefry2x32 partitionable (bit-exact rounds 2-8).

#define KWG    64
#define NTH    512
#define LSTEPS 32
#define DDIM   512
#define NOPS   16
#define NEGC   (-1.0e9f)

// ---------------- threefry2x32 core ----------------
static __device__ __forceinline__ void tf2x32(uint32_t k0, uint32_t k1,
                                              uint32_t c0, uint32_t c1,
                                              uint32_t& o0, uint32_t& o1){
  uint32_t ks2 = k0 ^ k1 ^ 0x1BD11BDAu;
  uint32_t x0 = c0 + k0;
  uint32_t x1 = c1 + k1;
#define TFR(r) { x0 += x1; x1 = (x1 << (r)) | (x1 >> (32 - (r))); x1 ^= x0; }
  TFR(13) TFR(15) TFR(26) TFR(6)
  x0 += k1;  x1 += ks2 + 1u;
  TFR(17) TFR(29) TFR(16) TFR(24)
  x0 += ks2; x1 += k0 + 2u;
  TFR(13) TFR(15) TFR(26) TFR(6)
  x0 += k0;  x1 += k1 + 3u;
  TFR(17) TFR(29) TFR(16) TFR(24)
  x0 += k1;  x1 += ks2 + 4u;
  TFR(13) TFR(15) TFR(26) TFR(6)
  x0 += ks2; x1 += k0 + 5u;
#undef TFR
  o0 = x0; o1 = x1;
}

static __device__ __forceinline__ float gumbel_bits(uint32_t bits){
  float f = __uint_as_float((bits >> 9) | 0x3f800000u) - 1.0f;
  float u = (f == 0.0f) ? 1.1754943508222875e-38f : f;
  return -logf(-logf(u));
}

static __device__ __forceinline__ float sigm(float x){
  return 1.0f / (1.0f + expf(-x));
}

static __device__ __forceinline__ float wredsum(float v){
  #pragma unroll
  for (int m = 32; m; m >>= 1) v += __shfl_xor(v, m, 64);
  return v;
}

// gather 8 elems at stride 64: d = 64k + lane  (global or LDS)
static __device__ __forceinline__ void gl8(const float* __restrict__ p, int lane, float* r){
  #pragma unroll
  for (int k = 0; k < 8; ++k) r[k] = p[(k << 6) + lane];
}

static __device__ __forceinline__ float dot8(const float* w, const float* x){
  float s = 0.f;
  #pragma unroll
  for (int k = 0; k < 8; ++k) s += w[k]*x[k];
  return s;
}

// ---------------- tagged-atomic helpers (relaxed agent, at MALL) ----------
static __device__ __forceinline__ uint64_t tpack(uint32_t tag, float f){
  return ((uint64_t)tag << 32) | (uint64_t)__float_as_uint(f);
}
static __device__ __forceinline__ uint64_t ald64(const uint64_t* p){
  return __hip_atomic_load(p, __ATOMIC_RELAXED, __HIP_MEMORY_SCOPE_AGENT);
}
// PUBLISH = atomic swap (RMW commits at coherence point immediately; plain
// sc1 stores may drain lazily — this is the r9 A/B variable)
static __device__ __forceinline__ void ast64(uint64_t* p, uint64_t v){
  (void)__hip_atomic_exchange(p, v, __ATOMIC_RELAXED, __HIP_MEMORY_SCOPE_AGENT);
}
static __device__ __forceinline__ float poll1(const uint64_t* p, uint32_t tag){
  uint64_t v = ald64(p);
  while ((uint32_t)(v >> 32) != tag){
    __builtin_amdgcn_s_sleep(1);
    v = ald64(p);
  }
  return __uint_as_float((uint32_t)v);
}
// poll 8 cells (d=64k+lane) into registers (aw1 register rows)
static __device__ __forceinline__ void poll8s(const uint64_t* base, int lane,
                                              uint32_t tag, float* r){
  uint64_t v[8];
  for (;;){
    #pragma unroll
    for (int k = 0; k < 8; ++k) v[k] = ald64(base + (k << 6) + lane);
    bool ok = true;
    #pragma unroll
    for (int k = 0; k < 8; ++k) ok &= ((uint32_t)(v[k] >> 32) == tag);
    if (ok) break;
    __builtin_amdgcn_s_sleep(1);
  }
  #pragma unroll
  for (int k = 0; k < 8; ++k) r[k] = __uint_as_float((uint32_t)v[k]);
}

__global__ void __launch_bounds__(NTH, 2)
Controller_60601988547087_kernel(const float* __restrict__ emb,
                                 const float* __restrict__ wih,
                                 const float* __restrict__ whh,
                                 const float* __restrict__ bih,
                                 const float* __restrict__ bhh,
                                 const float* __restrict__ wa1,
                                 const float* __restrict__ wa2,
                                 const float* __restrict__ idxfc,
                                 const float* __restrict__ opfc,
                                 float* __restrict__ out,
                                 uint64_t* __restrict__ ws64)
{
  const int tid  = threadIdx.x;
  const int wg   = blockIdx.x;
  const int wave = tid >> 6;              // 0..7
  const int lane = tid & 63;
  const int unit = (wg << 3) | wave;      // one hidden unit per wave, 512 total

  // workspace (u64 tagged cells)
  uint64_t* bufA64 = ws64;                // h1      [512]  tags 3t+2
  uint64_t* bufB64 = ws64 + 512;          // h2      [512]  tags 1, 3t+4
  uint64_t* hw2g64 = ws64 + 1024;         // W2.h1   [512]  tags 3t+3
  uint64_t* aw1g64 = ws64 + 1536;         // aw1 rows[32][512], row t tag 3t+2

  __shared__ float s_hc[DDIM];            // carry h (h2) staging
  __shared__ float s_h1[DDIM];            // h after cell1
  __shared__ float s_hw2[DDIM];           // h1 @ w_attn_2^T
  __shared__ float s_xproj[17 * 32];      // [op][wave][gate] static W_ih·emb[op]
  __shared__ float s_aproj[33 * 32];      // [row][wave][gate] W_ih·anchors[row]
  __shared__ float s_opfc[NOPS * DDIM];   // 32 KB op_fc
  __shared__ float s_logits[33];
  __shared__ float s_oplog[16];
  __shared__ int   s_ibc[2];

  // ---- weights register-stationary, gathered at d = 64k+lane ----
  float wihr[4][8], whhr[4][8], a1r[8], a2r[8], fcr[8], bsum[4];
  #pragma unroll
  for (int g = 0; g < 4; ++g){
    gl8(wih + (size_t)((g << 9) + unit) * DDIM, lane, wihr[g]);
    gl8(whh + (size_t)((g << 9) + unit) * DDIM, lane, whhr[g]);
    bsum[g] = bih[(g << 9) + unit] + bhh[(g << 9) + unit];
  }
  gl8(wa1 + (size_t)unit * DDIM, lane, a1r);
  gl8(wa2 + (size_t)unit * DDIM, lane, a2r);
  gl8(idxfc, lane, fcr);

  for (int i = tid; i < NOPS * DDIM; i += NTH) s_opfc[i] = opfc[i];
  if (tid < 32) s_aproj[tid] = 0.0f;      // aproj row 0: anchors[0] = zeros

  // ---- static x-projections: s_xproj[op][wave][g] = (W_ih · emb[op])[unit] ----
  for (int op = 0; op <= NOPS; ++op){
    float xc[8];
    gl8(emb + (size_t)op * DDIM, lane, xc);
    #pragma unroll
    for (int g = 0; g < 4; ++g){
      float xp = wredsum(dot8(wihr[g], xc));
      if (lane == 0) s_xproj[op * 32 + (wave << 2) + g] = xp;
    }
  }
  __syncthreads();

  // per-wave register cache of aw1 rows (row r owned by wave r&7, slot r>>3)
  float row0[8], row1[8], row2[8], row3[8];

  // ---- init: h0 = cell(emb[16],0,0) via xproj; publish bufB tag 1 ----
  float cst;
  {
    const float* xp = s_xproj + 16 * 32 + (wave << 2);
    float gi = sigm(xp[0] + bsum[0]);
    float go = sigm(xp[3] + bsum[3]);
    cst = gi * tanhf(xp[2] + bsum[2]);   // c=0: forget term vanishes exactly
    float h0 = go * tanhf(cst);
    if (lane == 0) ast64(bufB64 + unit, tpack(1u, h0));
  }
  s_hc[tid] = poll1(bufB64 + tid, 1u);   // stage carry h (= h0)
  __syncthreads();

  uint32_t key0 = 0u, key1v = 42u;       // jax.random.key(42) -> (0, 42)
  float ent_sum = 0.f, lp_sum = 0.f;
  int prev_op = NOPS;                    // inp0 = embedding[16]

  for (int t = 0; t < LSTEPS; ++t){
    const uint32_t tagA = 3u*(uint32_t)t + 2u;
    const uint32_t tagB = 3u*(uint32_t)t + 3u;
    const uint32_t tagC = 3u*(uint32_t)t + 4u;

    float hc8[8];
    gl8(s_hc, lane, hc8);                // h2^(t-1) (= anchors[t] for t>=1; h0 at t=0)

    // ========== Stage A (critical): cell1 = xproj[prev_op] + W_hh·h ==========
    {
      const float* xp = s_xproj + prev_op * 32 + (wave << 2);
      float p0 = wredsum(dot8(whhr[0], hc8));
      float p1 = wredsum(dot8(whhr[1], hc8));
      float p2 = wredsum(dot8(whhr[2], hc8));
      float p3 = wredsum(dot8(whhr[3], hc8));
      float gi = sigm(xp[0] + p0 + bsum[0]);
      float gf = sigm(xp[1] + p1 + bsum[1]);
      float go = sigm(xp[3] + p3 + bsum[3]);
      cst = gf * cst + gi * tanhf(xp[2] + p2 + bsum[2]);
      float hn = go * tanhf(cst);
      if (lane == 0) ast64(bufA64 + unit, tpack(tagA, hn));
    }
    // ---- hop-A shadow: aw1 row t publish, aproj row t, owner row fetch ----
    {
      float pa = wredsum(dot8(a1r, hc8));              // row t = W1·h2^(t-1)
      if (lane == 0) ast64(aw1g64 + (size_t)t * DDIM + unit, tpack(tagA, pa));
      if (t > 0){                                      // aproj[t] = W_ih·anchors[t]
        #pragma unroll
        for (int g = 0; g < 4; ++g){
          float ap = wredsum(dot8(wihr[g], hc8));
          if (lane == 0) s_aproj[t * 32 + (wave << 2) + g] = ap;
        }
      }
    }
    if (wave == (t & 7)){                              // owner caches row t
      const uint64_t* rb = aw1g64 + (size_t)t * DDIM;
      int slot = t >> 3;
      if      (slot == 0) poll8s(rb, lane, tagA, row0);
      else if (slot == 1) poll8s(rb, lane, tagA, row1);
      else if (slot == 2) poll8s(rb, lane, tagA, row2);
      else                poll8s(rb, lane, tagA, row3);
    }
    s_h1[tid] = poll1(bufA64 + tid, tagA);             // hop A
    __syncthreads();

    // ========== Stage B: publish hw2 slice; ghh in hop-B shadow ==========
    float ghh0, ghh1, ghh2, ghh3;
    float h18[8];
    gl8(s_h1, lane, h18);
    {
      float q = wredsum(dot8(a2r, h18));
      if (lane == 0) ast64(hw2g64 + unit, tpack(tagB, q));
    }
    ghh0 = wredsum(dot8(whhr[0], h18));                // shadow of hop B
    ghh1 = wredsum(dot8(whhr[1], h18));
    ghh2 = wredsum(dot8(whhr[2], h18));
    ghh3 = wredsum(dot8(whhr[3], h18));
    s_hw2[tid] = poll1(hw2g64 + tid, tagB);            // hop B
    __syncthreads();

    // ======== Node logits + sampling — EVERY WG, bit-identical ========
    int ni;
    float nlp_s = 0.f, nent_s = 0.f;
    uint32_t k2a_s = 0u, k2b_s = 0u;
    {
      float h2c[8];
      gl8(s_hw2, lane, h2c);
#define ROWDOT(RR, I)                                                          \
      { int i_ = (I);                                                          \
        if (i_ <= t){                                                          \
          float acc = 0.f;                                                     \
          _Pragma("unroll")                                                    \
          for (int k = 0; k < 8; ++k) acc += tanhf(RR[k] + h2c[k]) * fcr[k];   \
          acc = wredsum(acc);                                                  \
          if (lane == 0) s_logits[i_] = 2.5f * tanhf(acc / 5.0f);              \
        } }
      ROWDOT(row0, wave)
      ROWDOT(row1, wave + 8)
      ROWDOT(row2, wave + 16)
      ROWDOT(row3, wave + 24)
#undef ROWDOT
      __syncthreads();
      if (wave == 0){
        // split(key,3), partitionable/foldlike: row i = tf(key, (0, i))
        uint32_t s0 = 0, s1 = 0;
        if (lane < 3) tf2x32(key0, key1v, 0u, (uint32_t)lane, s0, s1);
        uint32_t k1a = __shfl(s0, 0, 64), k1b = __shfl(s1, 0, 64);
        k2a_s = __shfl(s0, 1, 64); k2b_s = __shfl(s1, 1, 64);
        uint32_t nk0 = __shfl(s0, 2, 64), nk1 = __shfl(s1, 2, 64);
        key0 = nk0; key1v = nk1;
        // 33 random bits: bits[i] = x0 ^ x1 of tf(k1, (0, i))
        uint32_t y0 = 0, y1 = 0;
        if (lane < 33) tf2x32(k1a, k1b, 0u, (uint32_t)lane, y0, y1);
        uint32_t bits = y0 ^ y1;
        float gmb   = gumbel_bits(bits);
        float logit = (lane < 33) ? ((lane <= t) ? s_logits[lane] : NEGC) : -3.0e38f;
        float cand  = (lane < 33) ? (logit + gmb) : -3.0e38f;
        float v = cand; int bi = lane;
        #pragma unroll
        for (int m = 32; m; m >>= 1){
          float ov = __shfl_xor(v, m, 64); int ob = __shfl_xor(bi, m, 64);
          if (ov > v || (ov == v && ob < bi)){ v = ov; bi = ob; }
        }
        int ni_ = bi;
        float lm = (lane < 33) ? logit : -3.0e38f;
        #pragma unroll
        for (int m = 32; m; m >>= 1) lm = fmaxf(lm, __shfl_xor(lm, m, 64));
        float ex   = (lane < 33) ? expf(logit - lm) : 0.f;
        float ssum = wredsum(ex);
        float lsm  = logit - lm - logf(ssum);
        nlp_s  = -__shfl(lsm, ni_, 64);
        float entc = (lane <= t) ? (-lsm * expf(lsm)) : 0.f;
        nent_s = wredsum(entc);
        if (lane == 0) s_ibc[0] = ni_;
      }
      __syncthreads();
      ni = s_ibc[0];
    }

    // ========== Stage C (critical, tiny): cell2 via aproj cache ==========
    {
      const float* ag = s_aproj + ni * 32 + (wave << 2);
      float gi = sigm(ag[0] + ghh0 + bsum[0]);
      float gf = sigm(ag[1] + ghh1 + bsum[1]);
      float go = sigm(ag[3] + ghh3 + bsum[3]);
      cst = gf * cst + gi * tanhf(ag[2] + ghh2 + bsum[2]);
      float hn = go * tanhf(cst);
      if (lane == 0) ast64(bufB64 + unit, tpack(tagC, hn));
    }
    s_hc[tid] = poll1(bufB64 + tid, tagC);             // hop C
    __syncthreads();

    // ========== Tail (critical): op logits + sample -> prev_op ==========
    {
      float h28[8];
      gl8(s_hc, lane, h28);
      #pragma unroll
      for (int jj = 0; jj < 2; ++jj){
        int i = wave + (jj << 3);
        float acc = 0.f;
        #pragma unroll
        for (int k = 0; k < 8; ++k) acc += s_opfc[i * DDIM + (k << 6) + lane] * h28[k];
        acc = wredsum(acc);
        if (lane == 0) s_oplog[i] = tanhf(acc / 5.0f);  // (2.5/2.5)=1 scale
      }
      __syncthreads();
    }
    int oi;
    {
      if (wave == 0){
        // 16 random bits: bits[i] = x0 ^ x1 of tf(k2, (0, i))
        uint32_t z0 = 0, z1 = 0;
        if (lane < 16) tf2x32(k2a_s, k2b_s, 0u, (uint32_t)lane, z0, z1);
        uint32_t bits = z0 ^ z1;
        float gmb   = gumbel_bits(bits);
        float logit = (lane < 16) ? s_oplog[lane] : -3.0e38f;
        float cand  = (lane < 16) ? (logit + gmb) : -3.0e38f;
        float v = cand; int bi = lane;
        #pragma unroll
        for (int m = 32; m; m >>= 1){
          float ov = __shfl_xor(v, m, 64); int ob = __shfl_xor(bi, m, 64);
          if (ov > v || (ov == v && ob < bi)){ v = ov; bi = ob; }
        }
        int oi_ = bi;
        float lm = (lane < 16) ? logit : -3.0e38f;
        #pragma unroll
        for (int m = 32; m; m >>= 1) lm = fmaxf(lm, __shfl_xor(lm, m, 64));
        float ex   = (lane < 16) ? expf(logit - lm) : 0.f;
        float ssum = wredsum(ex);
        float olsm = logit - lm - logf(ssum);
        float olp  = -__shfl(olsm, oi_, 64);
        float oent = wredsum((lane < 16) ? (-olsm * expf(olsm)) : 0.f);
        lp_sum  += nlp_s + olp;
        ent_sum += nent_s + oent;
        if (lane == 0){
          s_ibc[1] = oi_;
          if (wg == 0){
            out[2 * t]     = (float)ni;
            out[2 * t + 1] = (float)oi_;
          }
        }
      }
      __syncthreads();
      oi = s_ibc[1];
    }
    prev_op = oi;
  }

  if (wg == 0 && wave == 0 && lane == 0){
    out[64] = ent_sum;
    out[65] = lp_sum;
  }
}

extern "C" void kernel_launch(void* const* d_in, const int* in_sizes, int n_in,
                              void* d_out, int out_size, void* d_ws, size_t ws_size,
                              hipStream_t stream) {
  (void)in_sizes; (void)n_in; (void)out_size; (void)ws_size;
  const float* emb  = (const float*)d_in[0];
  const float* wih  = (const float*)d_in[1];
  const float* whh  = (const float*)d_in[2];
  const float* bih  = (const float*)d_in[3];
  const float* bhh  = (const float*)d_in[4];
  const float* wa1  = (const float*)d_in[5];
  const float* wa2  = (const float*)d_in[6];
  const float* ifc  = (const float*)d_in[7];
  const float* ofc  = (const float*)d_in[8];
  float* out = (float*)d_out;
  uint64_t* ws = (uint64_t*)d_ws;
  hipLaunchKernelGGL(Controller_60601988547087_kernel,
                     dim3(KWG), dim3(NTH), 0, stream,
                     emb, wih, whh, bih, bhh, wa1, wa2, ifc, ofc, out, ws);
}

// Round 10
// 417.758 us; speedup vs baseline: 1.4757x; 1.2766x over previous
//
#include <hip/hip_runtime.h>
#include <stdint.h>

// Persistent-kernel LSTM NAS controller rollout — tagged-cell dataflow +
// CANDIDATE SPECULATION (hop C eliminated).
// r5-r9: per round-trip cost ~4.4us is mechanism-invariant (intrinsic
// store->observe latency). So cut the hop COUNT: after hop A each wave
// computes cell2 output h2_cand[i] for EVERY candidate node index i (aproj
// cache makes this ~30 ALU ops per candidate) and publishes all t+1
// candidates CONCURRENTLY with the hop-B round trip. ni is computed
// redundantly+bit-identically by every WG, so each WG then reads candidate
// row ni directly — published ~4us earlier -> tag-poll completes in ~1
// iteration (~0.5us), not a full RT. cst selected by lane shuffle.
// Per-step chain: hop A -> hop B -> local(ni, select, op sample, cell1).
// 2 RTs/step instead of 3.
// 64 wgs x 512 thr; one unit per wave; weights register-stationary.
// Tags: A=3t+2 (h1, aw1 row t), B=3t+3 (hw2), Cand=3t+4; init h0 tag 1.
// RNG: JAX threefry2x32 partitionable (bit-exact rounds 2-9).

#define KWG    64
#define NTH    512
#define LSTEPS 32
#define DDIM   512
#define NOPS   16
#define NEGC   (-1.0e9f)

// ---------------- threefry2x32 core ----------------
static __device__ __forceinline__ void tf2x32(uint32_t k0, uint32_t k1,
                                              uint32_t c0, uint32_t c1,
                                              uint32_t& o0, uint32_t& o1){
  uint32_t ks2 = k0 ^ k1 ^ 0x1BD11BDAu;
  uint32_t x0 = c0 + k0;
  uint32_t x1 = c1 + k1;
#define TFR(r) { x0 += x1; x1 = (x1 << (r)) | (x1 >> (32 - (r))); x1 ^= x0; }
  TFR(13) TFR(15) TFR(26) TFR(6)
  x0 += k1;  x1 += ks2 + 1u;
  TFR(17) TFR(29) TFR(16) TFR(24)
  x0 += ks2; x1 += k0 + 2u;
  TFR(13) TFR(15) TFR(26) TFR(6)
  x0 += k0;  x1 += k1 + 3u;
  TFR(17) TFR(29) TFR(16) TFR(24)
  x0 += k1;  x1 += ks2 + 4u;
  TFR(13) TFR(15) TFR(26) TFR(6)
  x0 += ks2; x1 += k0 + 5u;
#undef TFR
  o0 = x0; o1 = x1;
}

static __device__ __forceinline__ float gumbel_bits(uint32_t bits){
  float f = __uint_as_float((bits >> 9) | 0x3f800000u) - 1.0f;
  float u = (f == 0.0f) ? 1.1754943508222875e-38f : f;
  return -logf(-logf(u));
}

static __device__ __forceinline__ float sigm(float x){
  return 1.0f / (1.0f + expf(-x));
}

static __device__ __forceinline__ float wredsum(float v){
  #pragma unroll
  for (int m = 32; m; m >>= 1) v += __shfl_xor(v, m, 64);
  return v;
}

// gather 8 elems at stride 64: d = 64k + lane  (global or LDS)
static __device__ __forceinline__ void gl8(const float* __restrict__ p, int lane, float* r){
  #pragma unroll
  for (int k = 0; k < 8; ++k) r[k] = p[(k << 6) + lane];
}

static __device__ __forceinline__ float dot8(const float* w, const float* x){
  float s = 0.f;
  #pragma unroll
  for (int k = 0; k < 8; ++k) s += w[k]*x[k];
  return s;
}

// ---------------- tagged-atomic helpers (relaxed agent, at MALL) ----------
static __device__ __forceinline__ uint64_t tpack(uint32_t tag, float f){
  return ((uint64_t)tag << 32) | (uint64_t)__float_as_uint(f);
}
static __device__ __forceinline__ uint64_t ald64(const uint64_t* p){
  return __hip_atomic_load(p, __ATOMIC_RELAXED, __HIP_MEMORY_SCOPE_AGENT);
}
static __device__ __forceinline__ void ast64(uint64_t* p, uint64_t v){
  __hip_atomic_store(p, v, __ATOMIC_RELAXED, __HIP_MEMORY_SCOPE_AGENT);
}
static __device__ __forceinline__ float poll1(const uint64_t* p, uint32_t tag){
  uint64_t v = ald64(p);
  while ((uint32_t)(v >> 32) != tag){
    __builtin_amdgcn_s_sleep(1);
    v = ald64(p);
  }
  return __uint_as_float((uint32_t)v);
}
// poll 8 cells (d=64k+lane) into registers (aw1 register rows)
static __device__ __forceinline__ void poll8s(const uint64_t* base, int lane,
                                              uint32_t tag, float* r){
  uint64_t v[8];
  for (;;){
    #pragma unroll
    for (int k = 0; k < 8; ++k) v[k] = ald64(base + (k << 6) + lane);
    bool ok = true;
    #pragma unroll
    for (int k = 0; k < 8; ++k) ok &= ((uint32_t)(v[k] >> 32) == tag);
    if (ok) break;
    __builtin_amdgcn_s_sleep(1);
  }
  #pragma unroll
  for (int k = 0; k < 8; ++k) r[k] = __uint_as_float((uint32_t)v[k]);
}

__global__ void __launch_bounds__(NTH, 2)
Controller_60601988547087_kernel(const float* __restrict__ emb,
                                 const float* __restrict__ wih,
                                 const float* __restrict__ whh,
                                 const float* __restrict__ bih,
                                 const float* __restrict__ bhh,
                                 const float* __restrict__ wa1,
                                 const float* __restrict__ wa2,
                                 const float* __restrict__ idxfc,
                                 const float* __restrict__ opfc,
                                 float* __restrict__ out,
                                 uint64_t* __restrict__ ws64)
{
  const int tid  = threadIdx.x;
  const int wg   = blockIdx.x;
  const int wave = tid >> 6;              // 0..7
  const int lane = tid & 63;
  const int unit = (wg << 3) | wave;      // one hidden unit per wave, 512 total

  // workspace (u64 tagged cells)
  uint64_t* bufA64 = ws64;                // h1      [512]      tags 3t+2
  uint64_t* bufB64 = ws64 + 512;          // h0 init [512]      tag 1
  uint64_t* hw2g64 = ws64 + 1024;         // W2.h1   [512]      tags 3t+3
  uint64_t* aw1g64 = ws64 + 1536;         // aw1 rows[32][512], row t tag 3t+2
  uint64_t* cand64 = ws64 + 1536 + 32*512;// h2 candidates [33][512], tags 3t+4

  __shared__ float s_hc[DDIM];            // carry h (selected h2) staging
  __shared__ float s_h1[DDIM];            // h after cell1
  __shared__ float s_hw2[DDIM];           // h1 @ w_attn_2^T
  __shared__ float s_xproj[17 * 32];      // [op][wave][gate] static W_ih·emb[op]
  __shared__ float s_aproj[33 * 33];      // [row][wave*4+g] stride 33 (bank-safe)
  __shared__ float s_opfc[NOPS * DDIM];   // 32 KB op_fc
  __shared__ float s_logits[33];
  __shared__ float s_oplog[16];
  __shared__ int   s_ibc[2];

  // ---- weights register-stationary, gathered at d = 64k+lane ----
  float wihr[4][8], whhr[4][8], a1r[8], a2r[8], fcr[8], bsum[4];
  #pragma unroll
  for (int g = 0; g < 4; ++g){
    gl8(wih + (size_t)((g << 9) + unit) * DDIM, lane, wihr[g]);
    gl8(whh + (size_t)((g << 9) + unit) * DDIM, lane, whhr[g]);
    bsum[g] = bih[(g << 9) + unit] + bhh[(g << 9) + unit];
  }
  gl8(wa1 + (size_t)unit * DDIM, lane, a1r);
  gl8(wa2 + (size_t)unit * DDIM, lane, a2r);
  gl8(idxfc, lane, fcr);

  for (int i = tid; i < NOPS * DDIM; i += NTH) s_opfc[i] = opfc[i];
  if (tid < 33) s_aproj[tid] = 0.0f;      // aproj row 0: anchors[0] = zeros

  // ---- static x-projections: s_xproj[op][wave][g] = (W_ih · emb[op])[unit] ----
  for (int op = 0; op <= NOPS; ++op){
    float xc[8];
    gl8(emb + (size_t)op * DDIM, lane, xc);
    #pragma unroll
    for (int g = 0; g < 4; ++g){
      float xp = wredsum(dot8(wihr[g], xc));
      if (lane == 0) s_xproj[op * 32 + (wave << 2) + g] = xp;
    }
  }
  __syncthreads();

  // per-wave register cache of aw1 rows (row r owned by wave r&7, slot r>>3)
  float row0[8], row1[8], row2[8], row3[8];

  // ---- init: h0 = cell(emb[16],0,0) via xproj; publish bufB tag 1 ----
  float cst;
  {
    const float* xp = s_xproj + 16 * 32 + (wave << 2);
    float gi = sigm(xp[0] + bsum[0]);
    float go = sigm(xp[3] + bsum[3]);
    cst = gi * tanhf(xp[2] + bsum[2]);   // c=0: forget term vanishes exactly
    float h0 = go * tanhf(cst);
    if (lane == 0) ast64(bufB64 + unit, tpack(1u, h0));
  }
  s_hc[tid] = poll1(bufB64 + tid, 1u);   // stage carry h (= h0)
  __syncthreads();

  uint32_t key0 = 0u, key1v = 42u;       // jax.random.key(42) -> (0, 42)
  float ent_sum = 0.f, lp_sum = 0.f;
  int prev_op = NOPS;                    // inp0 = embedding[16]

  for (int t = 0; t < LSTEPS; ++t){
    const uint32_t tagA = 3u*(uint32_t)t + 2u;
    const uint32_t tagB = 3u*(uint32_t)t + 3u;
    const uint32_t tagK = 3u*(uint32_t)t + 4u;   // candidates

    float hc8[8];
    gl8(s_hc, lane, hc8);                // h2^(t-1) (= anchors[t] for t>=1; h0 at t=0)

    // ========== Stage A (critical): cell1 = xproj[prev_op] + W_hh·h ==========
    {
      const float* xp = s_xproj + prev_op * 32 + (wave << 2);
      float p0 = wredsum(dot8(whhr[0], hc8));
      float p1 = wredsum(dot8(whhr[1], hc8));
      float p2 = wredsum(dot8(whhr[2], hc8));
      float p3 = wredsum(dot8(whhr[3], hc8));
      float gi = sigm(xp[0] + p0 + bsum[0]);
      float gf = sigm(xp[1] + p1 + bsum[1]);
      float go = sigm(xp[3] + p3 + bsum[3]);
      cst = gf * cst + gi * tanhf(xp[2] + p2 + bsum[2]);
      float hn = go * tanhf(cst);
      if (lane == 0) ast64(bufA64 + unit, tpack(tagA, hn));
    }
    // ---- hop-A shadow: aw1 row t publish, aproj row t, owner row fetch ----
    {
      float pa = wredsum(dot8(a1r, hc8));              // row t = W1·h2^(t-1)
      if (lane == 0) ast64(aw1g64 + (size_t)t * DDIM + unit, tpack(tagA, pa));
      if (t > 0){                                      // aproj[t] = W_ih·anchors[t]
        #pragma unroll
        for (int g = 0; g < 4; ++g){
          float ap = wredsum(dot8(wihr[g], hc8));
          if (lane == 0) s_aproj[t * 33 + (wave << 2) + g] = ap;
        }
      }
    }
    if (wave == (t & 7)){                              // owner caches row t
      const uint64_t* rb = aw1g64 + (size_t)t * DDIM;
      int slot = t >> 3;
      if      (slot == 0) poll8s(rb, lane, tagA, row0);
      else if (slot == 1) poll8s(rb, lane, tagA, row1);
      else if (slot == 2) poll8s(rb, lane, tagA, row2);
      else                poll8s(rb, lane, tagA, row3);
    }
    s_h1[tid] = poll1(bufA64 + tid, tagA);             // hop A (RT 1)
    __syncthreads();

    // ========== Stage B: publish hw2; ghh + h2 CANDIDATES in hop-B shadow ====
    float h18[8];
    gl8(s_h1, lane, h18);
    {
      float q = wredsum(dot8(a2r, h18));
      if (lane == 0) ast64(hw2g64 + unit, tpack(tagB, q));
    }
    float ghh0 = wredsum(dot8(whhr[0], h18));          // shadow of hop B
    float ghh1 = wredsum(dot8(whhr[1], h18));
    float ghh2 = wredsum(dot8(whhr[2], h18));
    float ghh3 = wredsum(dot8(whhr[3], h18));
    // ---- candidate cell2 for every possible ni: lane i owns candidate i ----
    float cst_cand = 0.f;
    if (lane <= t){
      const float* ag = s_aproj + lane * 33 + (wave << 2);
      float gi = sigm(ag[0] + ghh0 + bsum[0]);
      float gf = sigm(ag[1] + ghh1 + bsum[1]);
      float go = sigm(ag[3] + ghh3 + bsum[3]);
      cst_cand = gf * cst + gi * tanhf(ag[2] + ghh2 + bsum[2]);
      float h2c = go * tanhf(cst_cand);
      ast64(cand64 + (size_t)lane * DDIM + unit, tpack(tagK, h2c));
    }
    s_hw2[tid] = poll1(hw2g64 + tid, tagB);            // hop B (RT 2)
    __syncthreads();

    // ======== Node logits + sampling — EVERY WG, bit-identical ========
    int ni;
    float nlp_s = 0.f, nent_s = 0.f;
    uint32_t k2a_s = 0u, k2b_s = 0u;
    {
      float h2c[8];
      gl8(s_hw2, lane, h2c);
#define ROWDOT(RR, I)                                                          \
      { int i_ = (I);                                                          \
        if (i_ <= t){                                                          \
          float acc = 0.f;                                                     \
          _Pragma("unroll")                                                    \
          for (int k = 0; k < 8; ++k) acc += tanhf(RR[k] + h2c[k]) * fcr[k];   \
          acc = wredsum(acc);                                                  \
          if (lane == 0) s_logits[i_] = 2.5f * tanhf(acc / 5.0f);              \
        } }
      ROWDOT(row0, wave)
      ROWDOT(row1, wave + 8)
      ROWDOT(row2, wave + 16)
      ROWDOT(row3, wave + 24)
#undef ROWDOT
      __syncthreads();
      if (wave == 0){
        // split(key,3), partitionable/foldlike: row i = tf(key, (0, i))
        uint32_t s0 = 0, s1 = 0;
        if (lane < 3) tf2x32(key0, key1v, 0u, (uint32_t)lane, s0, s1);
        uint32_t k1a = __shfl(s0, 0, 64), k1b = __shfl(s1, 0, 64);
        k2a_s = __shfl(s0, 1, 64); k2b_s = __shfl(s1, 1, 64);
        uint32_t nk0 = __shfl(s0, 2, 64), nk1 = __shfl(s1, 2, 64);
        key0 = nk0; key1v = nk1;
        // 33 random bits: bits[i] = x0 ^ x1 of tf(k1, (0, i))
        uint32_t y0 = 0, y1 = 0;
        if (lane < 33) tf2x32(k1a, k1b, 0u, (uint32_t)lane, y0, y1);
        uint32_t bits = y0 ^ y1;
        float gmb   = gumbel_bits(bits);
        float logit = (lane < 33) ? ((lane <= t) ? s_logits[lane] : NEGC) : -3.0e38f;
        float cand  = (lane < 33) ? (logit + gmb) : -3.0e38f;
        float v = cand; int bi = lane;
        #pragma unroll
        for (int m = 32; m; m >>= 1){
          float ov = __shfl_xor(v, m, 64); int ob = __shfl_xor(bi, m, 64);
          if (ov > v || (ov == v && ob < bi)){ v = ov; bi = ob; }
        }
        int ni_ = bi;
        float lm = (lane < 33) ? logit : -3.0e38f;
        #pragma unroll
        for (int m = 32; m; m >>= 1) lm = fmaxf(lm, __shfl_xor(lm, m, 64));
        float ex   = (lane < 33) ? expf(logit - lm) : 0.f;
        float ssum = wredsum(ex);
        float lsm  = logit - lm - logf(ssum);
        nlp_s  = -__shfl(lsm, ni_, 64);
        float entc = (lane <= t) ? (-lsm * expf(lsm)) : 0.f;
        nent_s = wredsum(entc);
        if (lane == 0) s_ibc[0] = ni_;
      }
      __syncthreads();
      ni = s_ibc[0];
    }

    // ========== Select h2 = cand[ni] (published ~1 RT ago -> warm) ==========
    cst = __shfl(cst_cand, ni, 64);                    // own unit's cst
    s_hc[tid] = poll1(cand64 + (size_t)ni * DDIM + tid, tagK);
    __syncthreads();

    // ========== Tail (local): op logits + sample -> prev_op ==========
    {
      float h28[8];
      gl8(s_hc, lane, h28);
      #pragma unroll
      for (int jj = 0; jj < 2; ++jj){
        int i = wave + (jj << 3);
        float acc = 0.f;
        #pragma unroll
        for (int k = 0; k < 8; ++k) acc += s_opfc[i * DDIM + (k << 6) + lane] * h28[k];
        acc = wredsum(acc);
        if (lane == 0) s_oplog[i] = tanhf(acc / 5.0f);  // (2.5/2.5)=1 scale
      }
      __syncthreads();
    }
    int oi;
    {
      if (wave == 0){
        // 16 random bits: bits[i] = x0 ^ x1 of tf(k2, (0, i))
        uint32_t z0 = 0, z1 = 0;
        if (lane < 16) tf2x32(k2a_s, k2b_s, 0u, (uint32_t)lane, z0, z1);
        uint32_t bits = z0 ^ z1;
        float gmb   = gumbel_bits(bits);
        float logit = (lane < 16) ? s_oplog[lane] : -3.0e38f;
        float cand  = (lane < 16) ? (logit + gmb) : -3.0e38f;
        float v = cand; int bi = lane;
        #pragma unroll
        for (int m = 32; m; m >>= 1){
          float ov = __shfl_xor(v, m, 64); int ob = __shfl_xor(bi, m, 64);
          if (ov > v || (ov == v && ob < bi)){ v = ov; bi = ob; }
        }
        int oi_ = bi;
        float lm = (lane < 16) ? logit : -3.0e38f;
        #pragma unroll
        for (int m = 32; m; m >>= 1) lm = fmaxf(lm, __shfl_xor(lm, m, 64));
        float ex   = (lane < 16) ? expf(logit - lm) : 0.f;
        float ssum = wredsum(ex);
        float olsm = logit - lm - logf(ssum);
        float olp  = -__shfl(olsm, oi_, 64);
        float oent = wredsum((lane < 16) ? (-olsm * expf(olsm)) : 0.f);
        lp_sum  += nlp_s + olp;
        ent_sum += nent_s + oent;
        if (lane == 0){
          s_ibc[1] = oi_;
          if (wg == 0){
            out[2 * t]     = (float)ni;
            out[2 * t + 1] = (float)oi_;
          }
        }
      }
      __syncthreads();
      oi = s_ibc[1];
    }
    prev_op = oi;
  }

  if (wg == 0 && wave == 0 && lane == 0){
    out[64] = ent_sum;
    out[65] = lp_sum;
  }
}

extern "C" void kernel_launch(void* const* d_in, const int* in_sizes, int n_in,
                              void* d_out, int out_size, void* d_ws, size_t ws_size,
                              hipStream_t stream) {
  (void)in_sizes; (void)n_in; (void)out_size; (void)ws_size;
  const float* emb  = (const float*)d_in[0];
  const float* wih  = (const float*)d_in[1];
  const float* whh  = (const float*)d_in[2];
  const float* bih  = (const float*)d_in[3];
  const float* bhh  = (const float*)d_in[4];
  const float* wa1  = (const float*)d_in[5];
  const float* wa2  = (const float*)d_in[6];
  const float* ifc  = (const float*)d_in[7];
  const float* ofc  = (const float*)d_in[8];
  float* out = (float*)d_out;
  uint64_t* ws = (uint64_t*)d_ws;
  hipLaunchKernelGGL(Controller_60601988547087_kernel,
                     dim3(KWG), dim3(NTH), 0, stream,
                     emb, wih, whh, bih, bhh, wa1, wa2, ifc, ofc, out, ws);
}